// Round 1
// baseline (581.767 us; speedup 1.0000x reference)
//
#include <hip/hip_runtime.h>

#define NN 50000
#define NE 800000

// ws layout in floats
#define OFF_SX   0LL              // N*64 f32
#define OFF_SE   (64LL*NN)        // N*16 f32
#define OFF_DEG  (80LL*NN)        // N    f32
#define OFF_S2   (81LL*NN)        // N*32 f32
#define OFF_H    (113LL*NN)       // N*64 f32
#define OFF_Y2   (177LL*NN)       // N*32 f32
#define OFF_FLAGS (209LL*NN)      // 2 ints
// bytes to zero: accumulators [0, 113*NN) floats

__device__ __forceinline__ float ldf(const void* p, long long i, int bf16) {
  if (bf16) {
    unsigned short u = ((const unsigned short*)p)[i];
    return __uint_as_float(((unsigned)u) << 16);
  }
  return ((const float*)p)[i];
}

__device__ __forceinline__ unsigned short f2bf(float f) {
  unsigned u = __float_as_uint(f);
  unsigned r = (u + 0x7fffu + ((u >> 16) & 1u)) >> 16;
  return (unsigned short)r;
}

__device__ __forceinline__ int ldidx(const void* p, long long i, int i64) {
  return i64 ? (int)((const long long*)p)[i] : ((const int*)p)[i];
}

__device__ __forceinline__ float bcast(float v, int k) {
  return __uint_as_float(__builtin_amdgcn_readlane(__float_as_uint(v), k));
}

// ---------------- detect dtypes (runs first, 1 thread) ----------------
__global__ void k_detect(const void* ei, const void* x, int* flags) {
  if (blockIdx.x == 0 && threadIdx.x == 0) {
    // edge_index: int64 iff all odd int32 words are zero (values < 2^31)
    const int* p = (const int*)ei;
    int any = 0;
    for (int i = 0; i < 256; ++i) any |= p[2 * i + 1];
    flags[0] = (any == 0) ? 1 : 0;
    // x: bf16 iff even uint16 words look like bf16 of N(0,1) values
    const unsigned short* q = (const unsigned short*)x;
    int cnt = 0;
    for (int i = 0; i < 256; ++i) {
      unsigned short w = q[2 * i];
      int e = (w >> 7) & 0xff;
      if (w == 0 || (e >= 110 && e <= 140)) cnt++;
    }
    flags[1] = (cnt >= 192) ? 1 : 0;
  }
}

// ---------------- layer-1 scatter: Sx += x[src], Se += ea, deg += 1 ----------------
__global__ void k_scatter1(const void* __restrict__ x, const void* __restrict__ ea,
                           const void* __restrict__ ei, const int* __restrict__ flags,
                           float* __restrict__ Sx, float* __restrict__ Se,
                           float* __restrict__ deg) {
  long long wid = ((long long)blockIdx.x * blockDim.x + threadIdx.x) >> 6;
  int lane = threadIdx.x & 63;
  if (wid >= NE) return;
  int i64 = flags[0], bf = flags[1];
  int src = ldidx(ei, wid, i64);
  int dst = ldidx(ei, NE + wid, i64);
  float xv = ldf(x, (long long)src * 64 + lane, bf);
  atomicAdd(&Sx[(long long)dst * 64 + lane], xv);
  if (lane < 16) {
    float ev = ldf(ea, wid * 16 + lane, bf);
    atomicAdd(&Se[(long long)dst * 16 + lane], ev);
  }
  if (lane == 0) atomicAdd(&deg[dst], 1.0f);
}

// ---------------- layer-1 node GEMM + BN + ReLU -> H ----------------
__global__ __launch_bounds__(256) void k_node1(
    const void* __restrict__ x, const float* __restrict__ Sx,
    const float* __restrict__ Se, const float* __restrict__ deg,
    const void* __restrict__ W1_msg, const void* __restrict__ b1_msg,
    const void* __restrict__ W1_self, const void* __restrict__ b1_self,
    const void* __restrict__ gamma, const void* __restrict__ beta,
    const void* __restrict__ mean, const void* __restrict__ var,
    const int* __restrict__ flags, float* __restrict__ H) {
  int lane = threadIdx.x & 63;
  int bf = flags[1];
  // per-lane weight column j = lane
  float wself[64], wx[64], we[16];
#pragma unroll
  for (int k = 0; k < 64; ++k) wself[k] = ldf(W1_self, k * 64 + lane, bf);
#pragma unroll
  for (int k = 0; k < 64; ++k) wx[k] = ldf(W1_msg, k * 64 + lane, bf);
#pragma unroll
  for (int k = 0; k < 16; ++k) we[k] = ldf(W1_msg, (64 + k) * 64 + lane, bf);
  float bmsg = ldf(b1_msg, lane, bf);
  float bself = ldf(b1_self, lane, bf);
  float g = ldf(gamma, lane, bf), bt = ldf(beta, lane, bf);
  float mn = ldf(mean, lane, bf), vr = ldf(var, lane, bf);
  float scale = g * rsqrtf(vr + 1e-5f);
  float shift = bt - mn * scale;

  long long nwaves = ((long long)gridDim.x * blockDim.x) >> 6;
  for (long long n = ((long long)blockIdx.x * blockDim.x + threadIdx.x) >> 6; n < NN;
       n += nwaves) {
    float xv = ldf(x, n * 64 + lane, bf);
    float sxv = Sx[n * 64 + lane];
    float sev = (lane < 16) ? Se[n * 16 + lane] : 0.0f;
    float dg = deg[n];
    float a0 = fmaf(dg, bmsg, bself), a1 = 0.f, a2 = 0.f, a3 = 0.f;
#pragma unroll
    for (int k = 0; k < 64; k += 4) {
      a0 = fmaf(bcast(xv, k + 0), wself[k + 0], fmaf(bcast(sxv, k + 0), wx[k + 0], a0));
      a1 = fmaf(bcast(xv, k + 1), wself[k + 1], fmaf(bcast(sxv, k + 1), wx[k + 1], a1));
      a2 = fmaf(bcast(xv, k + 2), wself[k + 2], fmaf(bcast(sxv, k + 2), wx[k + 2], a2));
      a3 = fmaf(bcast(xv, k + 3), wself[k + 3], fmaf(bcast(sxv, k + 3), wx[k + 3], a3));
    }
#pragma unroll
    for (int k = 0; k < 16; k += 4) {
      a0 = fmaf(bcast(sev, k + 0), we[k + 0], a0);
      a1 = fmaf(bcast(sev, k + 1), we[k + 1], a1);
      a2 = fmaf(bcast(sev, k + 2), we[k + 2], a2);
      a3 = fmaf(bcast(sev, k + 3), we[k + 3], a3);
    }
    float h = (a0 + a1) + (a2 + a3);
    h = fmaf(h, scale, shift);
    h = fmaxf(h, 0.0f);
    H[n * 64 + lane] = h;
  }
}

// ---------------- project Y2 = H @ W2_msg[0:64,:]  (N x 32) ----------------
__global__ __launch_bounds__(256) void k_projY2(const float* __restrict__ H,
                                                const void* __restrict__ W2_msg,
                                                const int* __restrict__ flags,
                                                float* __restrict__ Y2) {
  int lane = threadIdx.x & 63;
  int bf = flags[1];
  int j = lane & 31;
  float w[64];
#pragma unroll
  for (int k = 0; k < 64; ++k) w[k] = ldf(W2_msg, k * 32 + j, bf);
  long long nwaves = ((long long)gridDim.x * blockDim.x) >> 6;
  for (long long n = ((long long)blockIdx.x * blockDim.x + threadIdx.x) >> 6; n < NN;
       n += nwaves) {
    float hv = H[n * 64 + lane];
    float a0 = 0.f, a1 = 0.f, a2 = 0.f, a3 = 0.f;
#pragma unroll
    for (int k = 0; k < 64; k += 4) {
      a0 = fmaf(bcast(hv, k + 0), w[k + 0], a0);
      a1 = fmaf(bcast(hv, k + 1), w[k + 1], a1);
      a2 = fmaf(bcast(hv, k + 2), w[k + 2], a2);
      a3 = fmaf(bcast(hv, k + 3), w[k + 3], a3);
    }
    if (lane < 32) Y2[n * 32 + j] = (a0 + a1) + (a2 + a3);
  }
}

// ---------------- layer-2 scatter: S2 += Y2[src]  (2 edges per wave) ----------------
__global__ void k_scatter2(const float* __restrict__ Y2, const void* __restrict__ ei,
                           const int* __restrict__ flags, float* __restrict__ S2) {
  long long wid = ((long long)blockIdx.x * blockDim.x + threadIdx.x) >> 6;
  int lane = threadIdx.x & 63;
  long long e = wid * 2 + (lane >> 5);
  int l = lane & 31;
  if (e >= NE) return;
  int i64 = flags[0];
  int src = ldidx(ei, e, i64);
  int dst = ldidx(ei, NE + e, i64);
  atomicAdd(&S2[(long long)dst * 32 + l], Y2[(long long)src * 32 + l]);
}

// ---------------- layer-2 node: out = H@W2_self + Se@W2e + deg*b2m + b2s + S2 ----------------
__global__ __launch_bounds__(256) void k_node2(
    const float* __restrict__ H, const float* __restrict__ Se,
    const float* __restrict__ deg, const float* __restrict__ S2,
    const void* __restrict__ W2_msg, const void* __restrict__ b2_msg,
    const void* __restrict__ W2_self, const void* __restrict__ b2_self,
    const int* __restrict__ flags, void* __restrict__ out) {
  int lane = threadIdx.x & 63;
  int bf = flags[1];
  int j = lane & 31;
  float wself[64], we[16];
#pragma unroll
  for (int k = 0; k < 64; ++k) wself[k] = ldf(W2_self, k * 32 + j, bf);
#pragma unroll
  for (int k = 0; k < 16; ++k) we[k] = ldf(W2_msg, (64 + k) * 32 + j, bf);
  float bm = ldf(b2_msg, j, bf);
  float bs = ldf(b2_self, j, bf);
  long long nwaves = ((long long)gridDim.x * blockDim.x) >> 6;
  for (long long n = ((long long)blockIdx.x * blockDim.x + threadIdx.x) >> 6; n < NN;
       n += nwaves) {
    float hv = H[n * 64 + lane];
    float sev = (lane < 16) ? Se[n * 16 + lane] : 0.0f;
    float dg = deg[n];
    float a0 = fmaf(dg, bm, bs) + S2[n * 32 + j];
    float a1 = 0.f, a2 = 0.f, a3 = 0.f;
#pragma unroll
    for (int k = 0; k < 64; k += 4) {
      a0 = fmaf(bcast(hv, k + 0), wself[k + 0], a0);
      a1 = fmaf(bcast(hv, k + 1), wself[k + 1], a1);
      a2 = fmaf(bcast(hv, k + 2), wself[k + 2], a2);
      a3 = fmaf(bcast(hv, k + 3), wself[k + 3], a3);
    }
#pragma unroll
    for (int k = 0; k < 16; k += 4) {
      a0 = fmaf(bcast(sev, k + 0), we[k + 0], a0);
      a1 = fmaf(bcast(sev, k + 1), we[k + 1], a1);
      a2 = fmaf(bcast(sev, k + 2), we[k + 2], a2);
      a3 = fmaf(bcast(sev, k + 3), we[k + 3], a3);
    }
    float o = (a0 + a1) + (a2 + a3);
    if (lane < 32) {
      if (bf)
        ((unsigned short*)out)[n * 32 + j] = f2bf(o);
      else
        ((float*)out)[n * 32 + j] = o;
    }
  }
}

extern "C" void kernel_launch(void* const* d_in, const int* in_sizes, int n_in,
                              void* d_out, int out_size, void* d_ws, size_t ws_size,
                              hipStream_t stream) {
  const void* x = d_in[0];
  const void* ei = d_in[1];
  const void* ea = d_in[2];
  const void* W1_msg = d_in[3];
  const void* b1_msg = d_in[4];
  const void* W1_self = d_in[5];
  const void* b1_self = d_in[6];
  const void* gamma = d_in[7];
  const void* beta = d_in[8];
  const void* mean = d_in[9];
  const void* var = d_in[10];
  const void* W2_msg = d_in[11];
  const void* b2_msg = d_in[12];
  const void* W2_self = d_in[13];
  const void* b2_self = d_in[14];

  float* ws = (float*)d_ws;
  float* Sx = ws + OFF_SX;
  float* Se = ws + OFF_SE;
  float* deg = ws + OFF_DEG;
  float* S2 = ws + OFF_S2;
  float* H = ws + OFF_H;
  float* Y2 = ws + OFF_Y2;
  int* flags = (int*)(ws + OFF_FLAGS);

  // dtype detection (int32/int64, f32/bf16)
  hipLaunchKernelGGL(k_detect, dim3(1), dim3(64), 0, stream, ei, x, flags);
  // zero accumulators: Sx, Se, deg, S2
  hipMemsetAsync(d_ws, 0, (size_t)(113LL * NN) * sizeof(float), stream);

  hipLaunchKernelGGL(k_scatter1, dim3((NE * 64) / 256), dim3(256), 0, stream, x, ea, ei,
                     flags, Sx, Se, deg);
  hipLaunchKernelGGL(k_node1, dim3(1024), dim3(256), 0, stream, x, Sx, Se, deg, W1_msg,
                     b1_msg, W1_self, b1_self, gamma, beta, mean, var, flags, H);
  hipLaunchKernelGGL(k_projY2, dim3(1024), dim3(256), 0, stream, H, W2_msg, flags, Y2);
  hipLaunchKernelGGL(k_scatter2, dim3((NE / 2 * 64) / 256), dim3(256), 0, stream, Y2, ei,
                     flags, S2);
  hipLaunchKernelGGL(k_node2, dim3(1024), dim3(256), 0, stream, H, Se, deg, S2, W2_msg,
                     b2_msg, W2_self, b2_self, flags, d_out);
}